// Round 3
// baseline (444.059 us; speedup 1.0000x reference)
//
#include <hip/hip_runtime.h>

typedef __attribute__((ext_vector_type(8))) short short8;
typedef __attribute__((ext_vector_type(8))) unsigned short ushort8;
typedef __attribute__((ext_vector_type(4))) float f32x4;
typedef unsigned short ushort;
typedef unsigned int uint;

// round-to-nearest-even f32 -> bf16 bits (used for We, one-time)
__device__ __forceinline__ ushort f2bf(float f) {
    uint x = __float_as_uint(f);
    x += 0x7fffu + ((x >> 16) & 1u);
    return (ushort)(x >> 16);
}

// cheap pack: round-half-up then v_perm_b32 packs the two high halves.
// dst low16 = bf16(x), high16 = bf16(y). 3 VALU per 2 elements.
__device__ __forceinline__ uint pack2bf(float x, float y) {
    uint xi = __float_as_uint(x) + 0x8000u;
    uint yi = __float_as_uint(y) + 0x8000u;
    return __builtin_amdgcn_perm(yi, xi, 0x07060302u);
}

// -------- kernel 1 (merged prep): blocks 0..63 convert We -> bf16;
// blocks 64..319: q_ws[b][o] = dot(query[b,:512], Wq[o,:512]) + bq[o] + be[o]
__global__ __launch_bounds__(256) void prep(
    const float* __restrict__ query, const float* __restrict__ Wq,
    const float* __restrict__ bq, const float* __restrict__ be,
    const float* __restrict__ We, float* __restrict__ q_ws,
    ushort* __restrict__ Web) {
    __shared__ float qrow[512];
    const int t = threadIdx.x;
    if (blockIdx.x < 64) {
        const int i = (blockIdx.x * 256 + t) * 4;
        float4 v = *(const float4*)(We + i);
        ushort4 u;
        u.x = f2bf(v.x); u.y = f2bf(v.y); u.z = f2bf(v.z); u.w = f2bf(v.w);
        *(ushort4*)(Web + i) = u;
        return;
    }
    const int b = blockIdx.x - 64;
    qrow[t]       = query[b * 512 + t];
    qrow[t + 256] = query[b * 512 + 256 + t];
    __syncthreads();
    const f32x4* wr = (const f32x4*)(Wq + (size_t)t * 512);
    float s0 = 0.f, s1 = 0.f, s2 = 0.f, s3 = 0.f;
#pragma unroll 4
    for (int j = 0; j < 128; j += 4) {
        f32x4 w0 = wr[j], w1 = wr[j + 1], w2 = wr[j + 2], w3 = wr[j + 3];
        f32x4 q0 = *(const f32x4*)(qrow + 4 * j);
        f32x4 q1 = *(const f32x4*)(qrow + 4 * j + 4);
        f32x4 q2 = *(const f32x4*)(qrow + 4 * j + 8);
        f32x4 q3 = *(const f32x4*)(qrow + 4 * j + 12);
        s0 += w0.x * q0.x + w0.y * q0.y + w0.z * q0.z + w0.w * q0.w;
        s1 += w1.x * q1.x + w1.y * q1.y + w1.z * q1.z + w1.w * q1.w;
        s2 += w2.x * q2.x + w2.y * q2.y + w2.z * q2.z + w2.w * q2.w;
        s3 += w3.x * q3.x + w3.y * q3.y + w3.z * q3.z + w3.w * q3.w;
    }
    q_ws[b * 256 + t] = (s0 + s1) + (s2 + s3) + bq[t] + be[t];
}

// -------- kernel 2: fused GEMM (e = ref@We^T) + tanh-scorer reduction
// M = 262144 rows, N = 256 (fully in acc), K = 256 (A fully in LDS).
// One barrier for A staging; K-loop barrier-free, B pipelined from L2.
#define BM 64
#define LDA 264   // bf16 stride = 132 dwords == 4 (mod 32): 2-way alias only

__global__ __launch_bounds__(256, 3) void fused_gemm(
    const float* __restrict__ ref, const ushort* __restrict__ Web,
    const float* __restrict__ q_ws, const float* __restrict__ Wv,
    const float* __restrict__ bv, float* __restrict__ out) {
    __shared__ ushort Asm[BM * LDA];   // 33792 B
    __shared__ float red[4][64];

    const int t = threadIdx.x;
    const int w = t >> 6;          // wave 0..3 -> col strip [64w, 64w+64)
    const int l = t & 63;
    const int quad = l >> 4;       // 0..3
    const int lr = l & 15;
    const size_t row0 = (size_t)blockIdx.x * BM;
    const int b = (int)(row0 >> 10);

    // ---- B k=0 prefetch (L2-resident), issued before A staging
    const ushort* Bp = Web + ((size_t)(w * 64 + lr)) * 256 + quad * 8;
    short8 bcur[4];
#pragma unroll
    for (int cb = 0; cb < 4; ++cb)
        bcur[cb] = *(const short8*)(Bp + cb * 16 * 256);

    // ---- stage FULL A tile: 64 rows x 256 cols, f32 -> bf16, one barrier
    {
        const int row = t >> 2;              // 4 threads per row
        const int colbase = (t & 3) * 64;    // 64 f32 each
        const float4* ap = (const float4*)(ref + (row0 + row) * 256 + colbase);
        uint* as = (uint*)(Asm + row * LDA + colbase);
#pragma unroll
        for (int c = 0; c < 2; ++c) {
            float4 buf[8];
#pragma unroll
            for (int j = 0; j < 8; ++j) buf[j] = ap[c * 8 + j];
#pragma unroll
            for (int j = 0; j < 4; ++j) {
                float4 x = buf[2 * j], y = buf[2 * j + 1];
                uint4 p;
                p.x = pack2bf(x.x, x.y);
                p.y = pack2bf(x.z, x.w);
                p.z = pack2bf(y.x, y.y);
                p.w = pack2bf(y.z, y.w);
                *(uint4*)(as + c * 16 + j * 4) = p;
            }
        }
    }

    // ---- epilogue operand prefetch (latency hidden under K-loop)
    const float* qe = q_ws + b * 256;
    const float wv0 = Wv[lr];
    const float wv1 = Wv[16 + lr];
    const float bvv = bv[0];
    float qv[4];
#pragma unroll
    for (int cb = 0; cb < 4; ++cb) qv[cb] = qe[w * 64 + cb * 16 + lr];

    __syncthreads();

    // ---- pipelined barrier-free K-loop
    f32x4 acc[4][4];
#pragma unroll
    for (int i = 0; i < 4; ++i)
#pragma unroll
        for (int j = 0; j < 4; ++j) acc[i][j] = (f32x4){0.f, 0.f, 0.f, 0.f};

    const ushort* Ap = Asm + lr * LDA + quad * 8;
#pragma unroll
    for (int k = 0; k < 8; ++k) {
        short8 bnxt[4];
        if (k < 7) {
#pragma unroll
            for (int cb = 0; cb < 4; ++cb)
                bnxt[cb] = *(const short8*)(Bp + cb * 16 * 256 + (k + 1) * 32);
        }
        short8 afr[4];
#pragma unroll
        for (int rb = 0; rb < 4; ++rb)
            afr[rb] = *(const short8*)(Ap + rb * 16 * LDA + k * 32);
#pragma unroll
        for (int rb = 0; rb < 4; ++rb)
#pragma unroll
            for (int cb = 0; cb < 4; ++cb)
                acc[rb][cb] = __builtin_amdgcn_mfma_f32_16x16x32_bf16(
                    afr[rb], bcur[cb], acc[rb][cb], 0, 0, 0);
        if (k < 7) {
#pragma unroll
            for (int cb = 0; cb < 4; ++cb) bcur[cb] = bnxt[cb];
        }
    }

    // ---- epilogue: out[row] = sum_n tanh(q[b,n] + e[row,n]) * Wv[n&31] + 8*bv
    float part[4][4];
#pragma unroll
    for (int rb = 0; rb < 4; ++rb)
#pragma unroll
        for (int r = 0; r < 4; ++r) part[rb][r] = 0.f;

#pragma unroll
    for (int cb = 0; cb < 4; ++cb) {
        const float wvv = (cb & 1) ? wv1 : wv0;   // (n & 31) = 16*(cb&1) + lr
#pragma unroll
        for (int rb = 0; rb < 4; ++rb)
#pragma unroll
            for (int r = 0; r < 4; ++r) {
                float x = acc[rb][cb][r] + qv[cb];
                float th = 1.f - 2.f / (__expf(2.f * x) + 1.f);
                part[rb][r] += th * wvv;
            }
    }
    // reduce across the 16 column-lanes (xor bits 0..3)
#pragma unroll
    for (int off = 1; off < 16; off <<= 1)
#pragma unroll
        for (int rb = 0; rb < 4; ++rb)
#pragma unroll
            for (int r = 0; r < 4; ++r)
                part[rb][r] += __shfl_xor(part[rb][r], off, 64);

    if (lr == 0) {
#pragma unroll
        for (int rb = 0; rb < 4; ++rb)
#pragma unroll
            for (int r = 0; r < 4; ++r)
                red[w][rb * 16 + quad * 4 + r] = part[rb][r];
    }
    __syncthreads();
    if (t < 64) {
        float s = red[0][t] + red[1][t] + red[2][t] + red[3][t] + 8.f * bvv;
        out[row0 + t] = s;
    }
}

extern "C" void kernel_launch(void* const* d_in, const int* in_sizes, int n_in,
                              void* d_out, int out_size, void* d_ws, size_t ws_size,
                              hipStream_t stream) {
    const float* query = (const float*)d_in[0];
    const float* ref   = (const float*)d_in[1];
    const float* Wq    = (const float*)d_in[2];
    const float* bq    = (const float*)d_in[3];
    const float* We    = (const float*)d_in[4];
    const float* be    = (const float*)d_in[5];
    const float* Wv    = (const float*)d_in[6];
    const float* bv    = (const float*)d_in[7];
    float* out = (float*)d_out;

    float*  q_ws = (float*)d_ws;                                   // 256 KB
    ushort* Web  = (ushort*)((char*)d_ws + 65536 * sizeof(float)); // 128 KB

    prep<<<320, 256, 0, stream>>>(query, Wq, bq, be, We, q_ws, Web);
    fused_gemm<<<4096, 256, 0, stream>>>(ref, Web, q_ws, Wv, bv, out);
}

// Round 4
// 419.427 us; speedup vs baseline: 1.0587x; 1.0587x over previous
//
#include <hip/hip_runtime.h>

typedef __attribute__((ext_vector_type(8))) short short8;
typedef __attribute__((ext_vector_type(8))) unsigned short ushort8;
typedef __attribute__((ext_vector_type(4))) float f32x4;
typedef unsigned short ushort;
typedef unsigned int uint;

__device__ __forceinline__ float fast_exp2(float x) {
#if __has_builtin(__builtin_amdgcn_exp2f)
    return __builtin_amdgcn_exp2f(x);
#else
    return __expf(x * 0.6931471805599453f);
#endif
}
__device__ __forceinline__ float fast_rcp(float x) {
#if __has_builtin(__builtin_amdgcn_rcpf)
    return __builtin_amdgcn_rcpf(x);
#else
    return __frcp_rn(x);
#endif
}

// round-to-nearest-even f32 -> bf16 bits (used for We, one-time)
__device__ __forceinline__ ushort f2bf(float f) {
    uint x = __float_as_uint(f);
    x += 0x7fffu + ((x >> 16) & 1u);
    return (ushort)(x >> 16);
}

// cheap pack: round-half-up + v_perm_b32. dst lo16=bf16(x), hi16=bf16(y).
__device__ __forceinline__ uint pack2bf(float x, float y) {
    uint xi = __float_as_uint(x) + 0x8000u;
    uint yi = __float_as_uint(y) + 0x8000u;
    return __builtin_amdgcn_perm(yi, xi, 0x07060302u);
}

// -------- kernel 1 (merged prep):
// blocks 0..63:  Web = bf16(We)
// blocks 64..319: q_ws[b][o] = dot(query[b],Wq[o]) + bq[o] + be[o]
// block 320:     aux[0] = 8*(sum(Wv) + bv)
__global__ __launch_bounds__(256) void prep(
    const float* __restrict__ query, const float* __restrict__ Wq,
    const float* __restrict__ bq, const float* __restrict__ be,
    const float* __restrict__ We, const float* __restrict__ Wv,
    const float* __restrict__ bv, float* __restrict__ q_ws,
    ushort* __restrict__ Web, float* __restrict__ aux) {
    __shared__ float qrow[512];
    const int t = threadIdx.x;
    if (blockIdx.x < 64) {
        const int i = (blockIdx.x * 256 + t) * 4;
        float4 v = *(const float4*)(We + i);
        ushort4 u;
        u.x = f2bf(v.x); u.y = f2bf(v.y); u.z = f2bf(v.z); u.w = f2bf(v.w);
        *(ushort4*)(Web + i) = u;
        return;
    }
    if (blockIdx.x == 320) {
        if (t >= 64) return;
        float v = (t < 32) ? Wv[t] : 0.f;
#pragma unroll
        for (int off = 1; off < 32; off <<= 1) v += __shfl_xor(v, off, 64);
        if (t == 0) aux[0] = 8.f * (v + bv[0]);
        return;
    }
    const int b = blockIdx.x - 64;
    qrow[t]       = query[b * 512 + t];
    qrow[t + 256] = query[b * 512 + 256 + t];
    __syncthreads();
    const f32x4* wr = (const f32x4*)(Wq + (size_t)t * 512);
    float s0 = 0.f, s1 = 0.f, s2 = 0.f, s3 = 0.f;
#pragma unroll 4
    for (int j = 0; j < 128; j += 4) {
        f32x4 w0 = wr[j], w1 = wr[j + 1], w2 = wr[j + 2], w3 = wr[j + 3];
        f32x4 q0 = *(const f32x4*)(qrow + 4 * j);
        f32x4 q1 = *(const f32x4*)(qrow + 4 * j + 4);
        f32x4 q2 = *(const f32x4*)(qrow + 4 * j + 8);
        f32x4 q3 = *(const f32x4*)(qrow + 4 * j + 12);
        s0 += w0.x * q0.x + w0.y * q0.y + w0.z * q0.z + w0.w * q0.w;
        s1 += w1.x * q1.x + w1.y * q1.y + w1.z * q1.z + w1.w * q1.w;
        s2 += w2.x * q2.x + w2.y * q2.y + w2.z * q2.z + w2.w * q2.w;
        s3 += w3.x * q3.x + w3.y * q3.y + w3.z * q3.z + w3.w * q3.w;
    }
    q_ws[b * 256 + t] = (s0 + s1) + (s2 + s3) + bq[t] + be[t];
}

// -------- kernel 2: fused GEMM (e = ref@We^T) + tanh-scorer reduction
// A LDS layout: fragment-slots. Region (rb,k) = 1024B holding 64 lanes x 16B
// at ((rb*8+k)*64 + lane)*16 -> ds_read_b128/ds_write_b128 both conflict-free.
#define BM 64

__global__ __launch_bounds__(256, 4) void fused_gemm(
    const float* __restrict__ ref, const ushort* __restrict__ Web,
    const float* __restrict__ q_ws, const float* __restrict__ Wv,
    const float* __restrict__ aux, float* __restrict__ out) {
    __shared__ uint4 Asm[2048];        // 32768 B, 16B-aligned slots
    __shared__ float red[4][64];

    const int t = threadIdx.x;
    const int w = t >> 6;          // wave 0..3 -> col strip [64w, 64w+64)
    const int l = t & 63;
    const int quad = l >> 4;       // 0..3
    const int lr = l & 15;
    const size_t row0 = (size_t)blockIdx.x * BM;
    const int b = (int)(row0 >> 10);

    // ---- stage FULL A tile, f32 -> bf16, into fragment-slot layout.
    // thread (w,quad,lr) owns row = w*16+lr, cols quad*8 + kb*32 (kb=0..7)
    {
        const float* ap = ref + (row0 + w * 16 + lr) * 256 + quad * 8;
#pragma unroll
        for (int half = 0; half < 2; ++half) {
            float4 f[8];
#pragma unroll
            for (int kb = 0; kb < 4; ++kb) {
                f[2 * kb]     = *(const float4*)(ap + (half * 4 + kb) * 32);
                f[2 * kb + 1] = *(const float4*)(ap + (half * 4 + kb) * 32 + 4);
            }
#pragma unroll
            for (int kb = 0; kb < 4; ++kb) {
                uint4 p;
                p.x = pack2bf(f[2 * kb].x,     f[2 * kb].y);
                p.y = pack2bf(f[2 * kb].z,     f[2 * kb].w);
                p.z = pack2bf(f[2 * kb + 1].x, f[2 * kb + 1].y);
                p.w = pack2bf(f[2 * kb + 1].z, f[2 * kb + 1].w);
                Asm[(w * 8 + half * 4 + kb) * 64 + l] = p;   // linear lane*16
            }
        }
    }

    // ---- B k=0 prefetch (L2-resident) + epilogue operand prefetch
    const ushort* Bp = Web + ((size_t)(w * 64 + lr)) * 256 + quad * 8;
    short8 bcur[4];
#pragma unroll
    for (int cb = 0; cb < 4; ++cb)
        bcur[cb] = *(const short8*)(Bp + cb * 16 * 256);

    const float c2l = 2.885390081777927f;   // 2*log2(e)
    const float* qe = q_ws + b * 256;
    const float w2a = -2.f * Wv[lr];
    const float w2b = -2.f * Wv[16 + lr];
    float qvc[4];
#pragma unroll
    for (int cb = 0; cb < 4; ++cb) qvc[cb] = qe[w * 64 + cb * 16 + lr] * c2l;

    __syncthreads();

    // ---- pipelined barrier-free K-loop
    f32x4 acc[4][4];
#pragma unroll
    for (int i = 0; i < 4; ++i)
#pragma unroll
        for (int j = 0; j < 4; ++j) acc[i][j] = (f32x4){0.f, 0.f, 0.f, 0.f};

    const ushort* As = (const ushort*)Asm;
#pragma unroll
    for (int k = 0; k < 8; ++k) {
        short8 bnxt[4];
        if (k < 7) {
#pragma unroll
            for (int cb = 0; cb < 4; ++cb)
                bnxt[cb] = *(const short8*)(Bp + cb * 16 * 256 + (k + 1) * 32);
        }
        short8 afr[4];
#pragma unroll
        for (int rb = 0; rb < 4; ++rb)
            afr[rb] = *(const short8*)(As + ((rb * 8 + k) * 64 + l) * 8);
#pragma unroll
        for (int rb = 0; rb < 4; ++rb)
#pragma unroll
            for (int cb = 0; cb < 4; ++cb)
                acc[rb][cb] = __builtin_amdgcn_mfma_f32_16x16x32_bf16(
                    afr[rb], bcur[cb], acc[rb][cb], 0, 0, 0);
        if (k < 7) {
#pragma unroll
            for (int cb = 0; cb < 4; ++cb) bcur[cb] = bnxt[cb];
        }
    }

    // ---- epilogue: sum_n tanh(q+e)*Wv = sum_n wv + sum_n w2*rcp(1+e^{2x})
    // (the constant sum_n wv term lives in aux[0], added once at the end)
    float part[4][4];
#pragma unroll
    for (int rb = 0; rb < 4; ++rb)
#pragma unroll
        for (int r = 0; r < 4; ++r) part[rb][r] = 0.f;

#pragma unroll
    for (int cb = 0; cb < 4; ++cb) {
        const float w2 = (cb & 1) ? w2b : w2a;   // (n&31) = 16*(cb&1) + lr
#pragma unroll
        for (int rb = 0; rb < 4; ++rb)
#pragma unroll
            for (int r = 0; r < 4; ++r) {
                float e = fast_exp2(fmaf(acc[rb][cb][r], c2l, qvc[cb]));
                part[rb][r] = fmaf(w2, fast_rcp(e + 1.f), part[rb][r]);
            }
    }
    // reduce across the 16 column-lanes (xor bits 0..3)
#pragma unroll
    for (int off = 1; off < 16; off <<= 1)
#pragma unroll
        for (int rb = 0; rb < 4; ++rb)
#pragma unroll
            for (int r = 0; r < 4; ++r)
                part[rb][r] += __shfl_xor(part[rb][r], off, 64);

    if (lr == 0) {
#pragma unroll
        for (int rb = 0; rb < 4; ++rb)
#pragma unroll
            for (int r = 0; r < 4; ++r)
                red[w][rb * 16 + quad * 4 + r] = part[rb][r];
    }
    __syncthreads();
    if (t < 64) {
        float s = red[0][t] + red[1][t] + red[2][t] + red[3][t] + aux[0];
        out[row0 + t] = s;
    }
}

extern "C" void kernel_launch(void* const* d_in, const int* in_sizes, int n_in,
                              void* d_out, int out_size, void* d_ws, size_t ws_size,
                              hipStream_t stream) {
    const float* query = (const float*)d_in[0];
    const float* ref   = (const float*)d_in[1];
    const float* Wq    = (const float*)d_in[2];
    const float* bq    = (const float*)d_in[3];
    const float* We    = (const float*)d_in[4];
    const float* be    = (const float*)d_in[5];
    const float* Wv    = (const float*)d_in[6];
    const float* bv    = (const float*)d_in[7];
    float* out = (float*)d_out;

    float*  q_ws = (float*)d_ws;                                    // 256 KB
    ushort* Web  = (ushort*)((char*)d_ws + 262144);                 // 128 KB
    float*  aux  = (float*)((char*)d_ws + 262144 + 131072);         // 4 B

    prep<<<321, 256, 0, stream>>>(query, Wq, bq, be, We, Wv, bv, q_ws, Web, aux);
    fused_gemm<<<4096, 256, 0, stream>>>(ref, Web, q_ws, Wv, aux, out);
}